// Round 7
// baseline (1635.252 us; speedup 1.0000x reference)
//
#include <hip/hip_runtime.h>
#include <math.h>

// Problem constants
#define BATCH 2
#define SEQ   2048
#define DMODEL 1024
#define NHEAD 16
#define DK    64
#define EPS   1e-6f

typedef unsigned short ushort_t;
typedef __attribute__((ext_vector_type(8))) __bf16 bf16x8;
typedef __attribute__((ext_vector_type(4))) float f32x4;
typedef __attribute__((ext_vector_type(4))) unsigned int uivec4;

union B8U { uivec4 u; bf16x8 v; };

__device__ __forceinline__ ushort_t f2b(float x) {
    union { float f; unsigned int u; } c; c.f = x;
    unsigned int r = (c.u + 0x7fffu + ((c.u >> 16) & 1u)) >> 16;
    return (ushort_t)r;
}
__device__ __forceinline__ float b2f(ushort_t b) {
    union { unsigned int u; float f; } c; c.u = ((unsigned int)b) << 16;
    return c.f;
}
__device__ __forceinline__ bf16x8 ld_frag_lds(const ushort_t* p) {
    B8U t; t.u = *reinterpret_cast<const uivec4*>(p); return t.v;
}
__device__ __forceinline__ bf16x8 ld_frag_glb(const ushort_t* p) {
    B8U t; t.u = *reinterpret_cast<const uivec4*>(p); return t.v;
}
__device__ __forceinline__ void gload_lds16(const ushort_t* g, ushort_t* l) {
    __builtin_amdgcn_global_load_lds(
        (const __attribute__((address_space(1))) unsigned int*)g,
        (__attribute__((address_space(3))) unsigned int*)l,
        16, 0, 0);
}
__device__ __forceinline__ f32x4 unpk2(unsigned int w0, unsigned int w1) {
    f32x4 o;
    o[0] = b2f((ushort_t)(w0 & 0xffffu));
    o[1] = b2f((ushort_t)(w0 >> 16));
    o[2] = b2f((ushort_t)(w1 & 0xffffu));
    o[3] = b2f((ushort_t)(w1 >> 16));
    return o;
}
#define MFMA16(a, b, c) __builtin_amdgcn_mfma_f32_16x16x32_bf16((a), (b), (c), 0, 0, 0)

// =============== mask -> bitmask: 1 bit per position, word-per-32-cols ===============
__global__ __launch_bounds__(256) void mask_to_bits(const int* __restrict__ mask,
                                                    unsigned int* __restrict__ bits) {
    const size_t widx = (size_t)blockIdx.x * 256 + threadIdx.x;
    const int4* src = reinterpret_cast<const int4*>(mask + widx * 32);
    unsigned int wv = 0;
    #pragma unroll
    for (int i = 0; i < 8; ++i) {
        int4 v = src[i];
        wv |= (v.x ? 1u : 0u) << (i * 4 + 0);
        wv |= (v.y ? 1u : 0u) << (i * 4 + 1);
        wv |= (v.z ? 1u : 0u) << (i * 4 + 2);
        wv |= (v.w ? 1u : 0u) << (i * 4 + 3);
    }
    bits[widx] = wv;
}

// =============== prep: fp32 -> bf16 for K,V,Q (elementwise, 8 elems/thread) ===============
__global__ __launch_bounds__(256) void cvt_bf16x3(const float* __restrict__ X0,
                                                  const float* __restrict__ X1,
                                                  const float* __restrict__ X2,
                                                  ushort_t* __restrict__ Y0,
                                                  ushort_t* __restrict__ Y1,
                                                  ushort_t* __restrict__ Y2) {
    const int z = blockIdx.y;
    const float* X = (z == 0) ? X0 : (z == 1) ? X1 : X2;
    ushort_t*    Y = (z == 0) ? Y0 : (z == 1) ? Y1 : Y2;
    const size_t i = ((size_t)blockIdx.x * 256 + threadIdx.x) * 8;
    float4 a = *reinterpret_cast<const float4*>(X + i);
    float4 b = *reinterpret_cast<const float4*>(X + i + 4);
    ushort_t o[8];
    o[0] = f2b(a.x); o[1] = f2b(a.y); o[2] = f2b(a.z); o[3] = f2b(a.w);
    o[4] = f2b(b.x); o[5] = f2b(b.y); o[6] = f2b(b.z); o[7] = f2b(b.w);
    *reinterpret_cast<uivec4*>(Y + i) = *reinterpret_cast<const uivec4*>(o);
}

// =============== prep: W fp32[k][n] -> Wt bf16[n][k] (64x64 LDS tiles) ===============
__global__ __launch_bounds__(256) void transpose_w3(const float* __restrict__ W0,
                                                    const float* __restrict__ W1,
                                                    const float* __restrict__ W2,
                                                    ushort_t* __restrict__ T0,
                                                    ushort_t* __restrict__ T1,
                                                    ushort_t* __restrict__ T2) {
    __shared__ ushort_t tile[64][68];
    const int z = blockIdx.z;
    const float* W = (z == 0) ? W0 : (z == 1) ? W1 : W2;
    ushort_t*    T = (z == 0) ? T0 : (z == 1) ? T1 : T2;
    const int k0 = blockIdx.x * 64;
    const int n0 = blockIdx.y * 64;
    const int t = threadIdx.x;
    {
        const int r = t >> 2, c0 = (t & 3) * 16;
        const float* src = W + (size_t)(k0 + r) * DMODEL + n0 + c0;
        #pragma unroll
        for (int i = 0; i < 16; ++i) tile[r][c0 + i] = f2b(src[i]);
    }
    __syncthreads();
    {
        const int c = t >> 2, r0 = (t & 3) * 16;
        ushort_t* dst = T + (size_t)(n0 + c) * DMODEL + k0 + r0;
        #pragma unroll
        for (int i = 0; i < 16; ++i) dst[i] = tile[r0 + i][c];
    }
}

// =============== bf16 MFMA projection GEMM (m97 structure): Y = Xb @ Wt^T ===============
__global__ __launch_bounds__(256) void gemm_proj3(const ushort_t* __restrict__ Xb0,
                                                  const ushort_t* __restrict__ Xb1,
                                                  const ushort_t* __restrict__ Xb2,
                                                  const ushort_t* __restrict__ Wt0,
                                                  const ushort_t* __restrict__ Wt1,
                                                  const ushort_t* __restrict__ Wt2,
                                                  ushort_t* __restrict__ Y0,
                                                  ushort_t* __restrict__ Y1,
                                                  ushort_t* __restrict__ Y2) {
    __shared__ __align__(16) ushort_t As[128 * 32];
    __shared__ __align__(16) ushort_t Bs[128 * 32];
    const int z = blockIdx.z;
    const ushort_t* Xb = (z == 0) ? Xb0 : (z == 1) ? Xb1 : Xb2;
    const ushort_t* Wt = (z == 0) ? Wt0 : (z == 1) ? Wt1 : Wt2;
    ushort_t*       Y  = (z == 0) ? Y0  : (z == 1) ? Y1  : Y2;

    const int t = threadIdx.x;
    const int bm = blockIdx.y * 128;
    const int bn = blockIdx.x * 128;
    const int w = t >> 6, lane = t & 63;
    const int ln16 = lane & 15, quad = lane >> 4;
    const int wr = w >> 1, wc = w & 1;

    const int srow = lane >> 2;
    const int selem = (lane & 3) * 8;

    f32x4 acc[4][4] = {};

    for (int k0 = 0; k0 < DMODEL; k0 += 32) {
        #pragma unroll
        for (int j = 0; j < 2; ++j) {
            const int g = w * 2 + j;           // 16-row group 0..7
            const int m = g * 16 + srow;
            gload_lds16(Xb + (size_t)(bm + m) * DMODEL + k0 + selem, &As[g * 512]);
            gload_lds16(Wt + (size_t)(bn + m) * DMODEL + k0 + selem, &Bs[g * 512]);
        }
        __syncthreads();
        bf16x8 af[4], bfr[4];
        #pragma unroll
        for (int rt = 0; rt < 4; ++rt)
            af[rt] = ld_frag_lds(&As[(wr * 64 + rt * 16 + ln16) * 32 + quad * 8]);
        #pragma unroll
        for (int ct = 0; ct < 4; ++ct)
            bfr[ct] = ld_frag_lds(&Bs[(wc * 64 + ct * 16 + ln16) * 32 + quad * 8]);
        #pragma unroll
        for (int rt = 0; rt < 4; ++rt)
            #pragma unroll
            for (int ct = 0; ct < 4; ++ct)
                acc[rt][ct] = MFMA16(af[rt], bfr[ct], acc[rt][ct]);
        __syncthreads();
    }
    #pragma unroll
    for (int rt = 0; rt < 4; ++rt) {
        #pragma unroll
        for (int ct = 0; ct < 4; ++ct) {
            #pragma unroll
            for (int r = 0; r < 4; ++r) {
                int row = bm + wr * 64 + rt * 16 + quad * 4 + r;
                int col = bn + wc * 64 + ct * 16 + ln16;
                Y[(size_t)row * DMODEL + col] = f2b(acc[rt][ct][r]);
            }
        }
    }
}

// =============== transpose V: v_up[b][seq][h*64+dk] -> v_t[(b*16+h)*64+dk][seq] ===============
__global__ __launch_bounds__(256) void transpose_v(const ushort_t* __restrict__ v_up,
                                                   ushort_t* __restrict__ v_t) {
    __shared__ ushort_t tile[64][68];
    const int t = threadIdx.x;
    const int s0 = blockIdx.x * 64;
    const int bh = blockIdx.y;
    const int b = bh >> 4, h = bh & 15;
    {
        const int r = t >> 2, c0 = (t & 3) * 16;
        const ushort_t* src = v_up + ((size_t)b * SEQ + s0 + r) * DMODEL + h * DK + c0;
        #pragma unroll
        for (int i = 0; i < 16; ++i) tile[r][c0 + i] = src[i];
    }
    __syncthreads();
    {
        const int c = t >> 2, r0 = (t & 3) * 16;
        ushort_t* dst = v_t + ((size_t)bh * DK + c) * SEQ + s0 + r0;
        #pragma unroll
        for (int i = 0; i < 16; ++i) dst[i] = tile[r0 + i][c];
    }
}

// =============== fused attention v4: two-pass recompute + coalesced attn write + XCD swizzle ===============
// block: (bh, q-tile of 32 rows), 512 threads (8 waves). VGPR-lean (no register P — v3's spill lesson).
// Pass 1: sweep K, row sums of exp(scores) in registers.
// Pass 2: recompute scores per 256-col block -> normalized bf16 P in Pb (LDS);
//         coalesced f32 attn write FROM Pb (full-line nontemporal); PV MFMA on the block.
// XCD swizzle: 4 consecutive bh per XCD -> K+V working set 2 MB < 4 MB L2.
#define PST 264   // P-buffer row stride in ushorts (256 + 8 pad; 528 B, 16B-aligned)
__global__ __launch_bounds__(512, 6) void attn_fused(const ushort_t* __restrict__ q_up,
                                                     const ushort_t* __restrict__ k_up,
                                                     const ushort_t* __restrict__ v_t,
                                                     const unsigned int* __restrict__ mbits,
                                                     float* __restrict__ attn,
                                                     float* __restrict__ o_ws) {
    __shared__ __align__(16) ushort_t Pb[32 * PST];   // 16,896 B
    __shared__ float psum[8][32];
    __shared__ float inv_s[32];

    const int t = threadIdx.x;
    const int w = t >> 6, lane = t & 63;
    const int ln16 = lane & 15, quad = lane >> 4;

    // XCD-aware remap: orig linear id -> (bh, q0) such that each XCD owns 4 consecutive bh.
    const int orig = blockIdx.x + gridDim.x * blockIdx.y;   // 0..2047
    const int j8 = orig >> 3;                               // 0..255
    const int bh = (orig & 7) * 4 + (j8 >> 6);              // 4 bh per XCD slot
    const int q0 = (j8 & 63) * 32;
    const int b = bh >> 4, h = bh & 15;

    // --- Q fragments (32 rows x 64 dk): A[m][k], m=ln16, k=quad*8+j
    bf16x8 aq[2][2];
    #pragma unroll
    for (int rt = 0; rt < 2; ++rt)
        #pragma unroll
        for (int ks = 0; ks < 2; ++ks)
            aq[rt][ks] = ld_frag_glb(
                &q_up[((size_t)b * SEQ + q0 + rt * 16 + ln16) * DMODEL + h * DK + ks * 32 + quad * 8]);

    const unsigned int* mrow = mbits + ((size_t)b * SEQ + q0) * (SEQ / 32);  // [row][64 words]
    const ushort_t* kbase = &k_up[(size_t)b * SEQ * DMODEL + h * DK + quad * 8];

    // --- pass 1: row sums of exp(scores)
    float rs[2][4] = {};
    for (int i = 0; i < 16; ++i) {
        const int kt = (i * 8 + w) * 16;
        bf16x8 bk0 = ld_frag_glb(kbase + (size_t)(kt + ln16) * DMODEL);
        bf16x8 bk1 = ld_frag_glb(kbase + (size_t)(kt + ln16) * DMODEL + 32);
        const int wi = kt >> 5;
        const int bsh = (kt & 16) + ln16;
        #pragma unroll
        for (int rt = 0; rt < 2; ++rt) {
            f32x4 c = {0.f, 0.f, 0.f, 0.f};
            c = MFMA16(aq[rt][0], bk0, c);
            c = MFMA16(aq[rt][1], bk1, c);
            #pragma unroll
            for (int r = 0; r < 4; ++r) {
                const int row = rt * 16 + quad * 4 + r;
                const unsigned int mw = mrow[(size_t)row * (SEQ / 32) + wi];
                const float p = ((mw >> bsh) & 1u) ? 0.f : __expf(c[r] * 0.125f);
                rs[rt][r] += p;
            }
        }
    }
    // reduce over the 16 lanes of each quad-group (cols live in ln16)
    #pragma unroll
    for (int rt = 0; rt < 2; ++rt)
        #pragma unroll
        for (int r = 0; r < 4; ++r) {
            float v = rs[rt][r];
            v += __shfl_xor(v, 1);
            v += __shfl_xor(v, 2);
            v += __shfl_xor(v, 4);
            v += __shfl_xor(v, 8);
            rs[rt][r] = v;
        }
    if (ln16 == 0) {
        #pragma unroll
        for (int rt = 0; rt < 2; ++rt)
            #pragma unroll
            for (int r = 0; r < 4; ++r)
                psum[w][rt * 16 + quad * 4 + r] = rs[rt][r];
    }
    __syncthreads();
    if (t < 32) {
        float s = 0.f;
        #pragma unroll
        for (int j = 0; j < 8; ++j) s += psum[j][t];
        inv_s[t] = 1.f / s;
    }
    __syncthreads();
    float invr[2][4];
    #pragma unroll
    for (int rt = 0; rt < 2; ++rt)
        #pragma unroll
        for (int r = 0; r < 4; ++r)
            invr[rt][r] = inv_s[rt * 16 + quad * 4 + r];

    // --- pass 2: recompute scores per 256-col block -> Pb, coalesced attn write, PV
    const int prt = w >> 2, pct = w & 3;                 // this wave's PV output tile
    f32x4 acc = {0.f, 0.f, 0.f, 0.f};
    const ushort_t* vbase = &v_t[((size_t)bh * DK + pct * 16 + ln16) * SEQ + quad * 8];
    float* abase = attn + ((size_t)bh * SEQ + q0) * SEQ;
    const ushort_t* prow = &Pb[(prt * 16 + ln16) * PST + quad * 8];
    const int arow = t >> 4;                 // attn-write row (0..31)
    const int acol0 = (t & 15) * 16;         // attn-write col base within block

    for (int kb = 0; kb < SEQ; kb += 256) {
        #pragma unroll
        for (int tl = 0; tl < 2; ++tl) {
            const int kt = kb + (w * 2 + tl) * 16;
            bf16x8 bk0 = ld_frag_glb(kbase + (size_t)(kt + ln16) * DMODEL);
            bf16x8 bk1 = ld_frag_glb(kbase + (size_t)(kt + ln16) * DMODEL + 32);
            const int wi = kt >> 5;
            const int bsh = (kt & 16) + ln16;
            #pragma unroll
            for (int rt = 0; rt < 2; ++rt) {
                f32x4 c = {0.f, 0.f, 0.f, 0.f};
                c = MFMA16(aq[rt][0], bk0, c);
                c = MFMA16(aq[rt][1], bk1, c);
                #pragma unroll
                for (int r = 0; r < 4; ++r) {
                    const int row = rt * 16 + quad * 4 + r;
                    const unsigned int mw = mrow[(size_t)row * (SEQ / 32) + wi];
                    const float p = ((mw >> bsh) & 1u) ? 0.f : __expf(c[r] * 0.125f);
                    Pb[row * PST + (kt - kb) + ln16] = f2b(p * invr[rt][r]);
                }
            }
        }
        __syncthreads();
        // coalesced attn write: each 16-lane group streams one contiguous 1 KB f32 row chunk
        {
            const ushort_t* srcp = &Pb[arow * PST + acol0];
            float* dst = abase + (size_t)arow * SEQ + kb + acol0;
            const uivec4 pa = *reinterpret_cast<const uivec4*>(srcp);
            const uivec4 pb2 = *reinterpret_cast<const uivec4*>(srcp + 8);
            __builtin_nontemporal_store(unpk2(pa[0], pa[1]), reinterpret_cast<f32x4*>(dst));
            __builtin_nontemporal_store(unpk2(pa[2], pa[3]), reinterpret_cast<f32x4*>(dst + 4));
            __builtin_nontemporal_store(unpk2(pb2[0], pb2[1]), reinterpret_cast<f32x4*>(dst + 8));
            __builtin_nontemporal_store(unpk2(pb2[2], pb2[3]), reinterpret_cast<f32x4*>(dst + 12));
        }
        // PV on the block
        #pragma unroll
        for (int k0 = 0; k0 < 256; k0 += 32) {
            bf16x8 a  = ld_frag_lds(prow + k0);
            bf16x8 vb = ld_frag_glb(vbase + kb + k0);
            acc = MFMA16(a, vb, acc);
        }
        __syncthreads();
    }
    // epilogue
    #pragma unroll
    for (int r = 0; r < 4; ++r) {
        const int row = q0 + prt * 16 + quad * 4 + r;
        const int col = h * DK + pct * 16 + ln16;
        o_ws[((size_t)b * SEQ + row) * DMODEL + col] = acc[r];
    }
}

// =============== residual + layernorm ===============
__global__ __launch_bounds__(256) void ln_kernel(const float* __restrict__ O,
                                                 const float* __restrict__ Qin,
                                                 const float* __restrict__ g,
                                                 const float* __restrict__ bt,
                                                 float* __restrict__ out) {
    __shared__ float sm[256];
    const int tid = threadIdx.x;
    const size_t base = (size_t)blockIdx.x * DMODEL;
    float v[4];
    float s = 0.f, s2 = 0.f;
    #pragma unroll
    for (int i = 0; i < 4; ++i) {
        int d = tid + i * 256;
        float x = O[base + d] + Qin[base + d];
        v[i] = x;
        s += x;
        s2 += x * x;
    }
    sm[tid] = s; __syncthreads();
    for (int st = 128; st > 0; st >>= 1) {
        if (tid < st) sm[tid] += sm[tid + st];
        __syncthreads();
    }
    s = sm[0]; __syncthreads();
    sm[tid] = s2; __syncthreads();
    for (int st = 128; st > 0; st >>= 1) {
        if (tid < st) sm[tid] += sm[tid + st];
        __syncthreads();
    }
    s2 = sm[0];
    const float mu = s * (1.0f / DMODEL);
    const float var = s2 * (1.0f / DMODEL) - mu * mu;
    const float r = rsqrtf(var + EPS);
    #pragma unroll
    for (int i = 0; i < 4; ++i) {
        int d = tid + i * 256;
        out[base + d] = (v[i] - mu) * r * g[d] + bt[d];
    }
}

extern "C" void kernel_launch(void* const* d_in, const int* in_sizes, int n_in,
                              void* d_out, int out_size, void* d_ws, size_t ws_size,
                              hipStream_t stream) {
    const float* key   = (const float*)d_in[0];
    const float* value = (const float*)d_in[1];
    const float* query = (const float*)d_in[2];
    const int*   mask  = (const int*)  d_in[3];
    const float* W_k   = (const float*)d_in[4];
    const float* W_v   = (const float*)d_in[5];
    const float* W_q   = (const float*)d_in[6];
    const float* ln_g  = (const float*)d_in[7];
    const float* ln_b  = (const float*)d_in[8];

    float* out      = (float*)d_out;                       // normed: B*L*D
    float* attn_out = out + (size_t)BATCH * SEQ * DMODEL;  // attn: B*H*L*L

    const size_t NPROJ = (size_t)BATCH * SEQ * DMODEL;     // 4,194,304
    const size_t NW    = (size_t)DMODEL * DMODEL;          // 1,048,576
    ushort_t* k_up = (ushort_t*)d_ws;
    ushort_t* v_up = k_up + NPROJ;
    ushort_t* q_up = v_up + NPROJ;
    ushort_t* v_t  = q_up + NPROJ;
    ushort_t* kb   = v_t + NPROJ;
    ushort_t* vb   = kb + NPROJ;
    ushort_t* qb   = vb + NPROJ;
    ushort_t* wtk  = qb + NPROJ;
    ushort_t* wtv  = wtk + NW;
    ushort_t* wtq  = wtv + NW;
    float*    o_ws = (float*)(wtq + NW);
    unsigned int* mbits = (unsigned int*)(o_ws + NPROJ);   // B*SEQ*64 words = 1 MiB

    const int nwords = BATCH * SEQ * (SEQ / 32);           // 262,144
    mask_to_bits<<<nwords / 256, 256, 0, stream>>>(mask, mbits);

    dim3 gcvt((unsigned)(NPROJ / (256 * 8)), 3);           // (2048, 3)
    cvt_bf16x3<<<gcvt, 256, 0, stream>>>(key, value, query, kb, vb, qb);

    dim3 gtw(DMODEL / 64, DMODEL / 64, 3);                 // (16, 16, 3)
    transpose_w3<<<gtw, 256, 0, stream>>>(W_k, W_v, W_q, wtk, wtv, wtq);

    dim3 gproj(DMODEL / 128, (BATCH * SEQ) / 128, 3);      // (8, 32, 3)
    gemm_proj3<<<gproj, 256, 0, stream>>>(kb, vb, qb, wtk, wtv, wtq, k_up, v_up, q_up);

    dim3 gtr(SEQ / 64, BATCH * NHEAD);                     // (32, 32)
    transpose_v<<<gtr, 256, 0, stream>>>(v_up, v_t);

    dim3 gat(SEQ / 32, BATCH * NHEAD);                     // (64, 32)
    attn_fused<<<gat, 512, 0, stream>>>(q_up, k_up, v_t, mbits, attn_out, o_ws);

    ln_kernel<<<BATCH * SEQ, 256, 0, stream>>>(o_ws, query, ln_g, ln_b, out);
}

// Round 8
// 1419.577 us; speedup vs baseline: 1.1519x; 1.1519x over previous
//
#include <hip/hip_runtime.h>
#include <math.h>

// Problem constants
#define BATCH 2
#define SEQ   2048
#define DMODEL 1024
#define NHEAD 16
#define DK    64
#define EPS   1e-6f

typedef unsigned short ushort_t;
typedef __attribute__((ext_vector_type(8))) __bf16 bf16x8;
typedef __attribute__((ext_vector_type(4))) float f32x4;
typedef __attribute__((ext_vector_type(4))) unsigned int uivec4;

union B8U { uivec4 u; bf16x8 v; };

__device__ __forceinline__ ushort_t f2b(float x) {
    union { float f; unsigned int u; } c; c.f = x;
    unsigned int r = (c.u + 0x7fffu + ((c.u >> 16) & 1u)) >> 16;
    return (ushort_t)r;
}
__device__ __forceinline__ float b2f(ushort_t b) {
    union { unsigned int u; float f; } c; c.u = ((unsigned int)b) << 16;
    return c.f;
}
__device__ __forceinline__ bf16x8 ld_frag_lds(const ushort_t* p) {
    B8U t; t.u = *reinterpret_cast<const uivec4*>(p); return t.v;
}
__device__ __forceinline__ bf16x8 ld_frag_glb(const ushort_t* p) {
    B8U t; t.u = *reinterpret_cast<const uivec4*>(p); return t.v;
}
__device__ __forceinline__ void gload_lds16(const ushort_t* g, ushort_t* l) {
    __builtin_amdgcn_global_load_lds(
        (const __attribute__((address_space(1))) unsigned int*)g,
        (__attribute__((address_space(3))) unsigned int*)l,
        16, 0, 0);
}
__device__ __forceinline__ f32x4 unpk2(unsigned int w0, unsigned int w1) {
    f32x4 o;
    o[0] = b2f((ushort_t)(w0 & 0xffffu));
    o[1] = b2f((ushort_t)(w0 >> 16));
    o[2] = b2f((ushort_t)(w1 & 0xffffu));
    o[3] = b2f((ushort_t)(w1 >> 16));
    return o;
}
#define MFMA16(a, b, c) __builtin_amdgcn_mfma_f32_16x16x32_bf16((a), (b), (c), 0, 0, 0)

// =============== mask -> bitmask: 1 bit per position, word-per-32-cols ===============
__global__ __launch_bounds__(256) void mask_to_bits(const int* __restrict__ mask,
                                                    unsigned int* __restrict__ bits) {
    const size_t widx = (size_t)blockIdx.x * 256 + threadIdx.x;
    const int4* src = reinterpret_cast<const int4*>(mask + widx * 32);
    unsigned int wv = 0;
    #pragma unroll
    for (int i = 0; i < 8; ++i) {
        int4 v = src[i];
        wv |= (v.x ? 1u : 0u) << (i * 4 + 0);
        wv |= (v.y ? 1u : 0u) << (i * 4 + 1);
        wv |= (v.z ? 1u : 0u) << (i * 4 + 2);
        wv |= (v.w ? 1u : 0u) << (i * 4 + 3);
    }
    bits[widx] = wv;
}

// =============== prep: fp32 -> bf16 for K,V,Q (elementwise, 8 elems/thread) ===============
__global__ __launch_bounds__(256) void cvt_bf16x3(const float* __restrict__ X0,
                                                  const float* __restrict__ X1,
                                                  const float* __restrict__ X2,
                                                  ushort_t* __restrict__ Y0,
                                                  ushort_t* __restrict__ Y1,
                                                  ushort_t* __restrict__ Y2) {
    const int z = blockIdx.y;
    const float* X = (z == 0) ? X0 : (z == 1) ? X1 : X2;
    ushort_t*    Y = (z == 0) ? Y0 : (z == 1) ? Y1 : Y2;
    const size_t i = ((size_t)blockIdx.x * 256 + threadIdx.x) * 8;
    float4 a = *reinterpret_cast<const float4*>(X + i);
    float4 b = *reinterpret_cast<const float4*>(X + i + 4);
    ushort_t o[8];
    o[0] = f2b(a.x); o[1] = f2b(a.y); o[2] = f2b(a.z); o[3] = f2b(a.w);
    o[4] = f2b(b.x); o[5] = f2b(b.y); o[6] = f2b(b.z); o[7] = f2b(b.w);
    *reinterpret_cast<uivec4*>(Y + i) = *reinterpret_cast<const uivec4*>(o);
}

// =============== prep: W fp32[k][n] -> Wt bf16[n][k] (64x64 LDS tiles) ===============
__global__ __launch_bounds__(256) void transpose_w3(const float* __restrict__ W0,
                                                    const float* __restrict__ W1,
                                                    const float* __restrict__ W2,
                                                    ushort_t* __restrict__ T0,
                                                    ushort_t* __restrict__ T1,
                                                    ushort_t* __restrict__ T2) {
    __shared__ ushort_t tile[64][68];
    const int z = blockIdx.z;
    const float* W = (z == 0) ? W0 : (z == 1) ? W1 : W2;
    ushort_t*    T = (z == 0) ? T0 : (z == 1) ? T1 : T2;
    const int k0 = blockIdx.x * 64;
    const int n0 = blockIdx.y * 64;
    const int t = threadIdx.x;
    {
        const int r = t >> 2, c0 = (t & 3) * 16;
        const float* src = W + (size_t)(k0 + r) * DMODEL + n0 + c0;
        #pragma unroll
        for (int i = 0; i < 16; ++i) tile[r][c0 + i] = f2b(src[i]);
    }
    __syncthreads();
    {
        const int c = t >> 2, r0 = (t & 3) * 16;
        ushort_t* dst = T + (size_t)(n0 + c) * DMODEL + k0 + r0;
        #pragma unroll
        for (int i = 0; i < 16; ++i) dst[i] = tile[r0 + i][c];
    }
}

// =============== bf16 MFMA projection GEMM (m97 structure): Y = Xb @ Wt^T ===============
__global__ __launch_bounds__(256) void gemm_proj3(const ushort_t* __restrict__ Xb0,
                                                  const ushort_t* __restrict__ Xb1,
                                                  const ushort_t* __restrict__ Xb2,
                                                  const ushort_t* __restrict__ Wt0,
                                                  const ushort_t* __restrict__ Wt1,
                                                  const ushort_t* __restrict__ Wt2,
                                                  ushort_t* __restrict__ Y0,
                                                  ushort_t* __restrict__ Y1,
                                                  ushort_t* __restrict__ Y2) {
    __shared__ __align__(16) ushort_t As[128 * 32];
    __shared__ __align__(16) ushort_t Bs[128 * 32];
    const int z = blockIdx.z;
    const ushort_t* Xb = (z == 0) ? Xb0 : (z == 1) ? Xb1 : Xb2;
    const ushort_t* Wt = (z == 0) ? Wt0 : (z == 1) ? Wt1 : Wt2;
    ushort_t*       Y  = (z == 0) ? Y0  : (z == 1) ? Y1  : Y2;

    const int t = threadIdx.x;
    const int bm = blockIdx.y * 128;
    const int bn = blockIdx.x * 128;
    const int w = t >> 6, lane = t & 63;
    const int ln16 = lane & 15, quad = lane >> 4;
    const int wr = w >> 1, wc = w & 1;

    const int srow = lane >> 2;
    const int selem = (lane & 3) * 8;

    f32x4 acc[4][4] = {};

    for (int k0 = 0; k0 < DMODEL; k0 += 32) {
        #pragma unroll
        for (int j = 0; j < 2; ++j) {
            const int g = w * 2 + j;           // 16-row group 0..7
            const int m = g * 16 + srow;
            gload_lds16(Xb + (size_t)(bm + m) * DMODEL + k0 + selem, &As[g * 512]);
            gload_lds16(Wt + (size_t)(bn + m) * DMODEL + k0 + selem, &Bs[g * 512]);
        }
        __syncthreads();
        bf16x8 af[4], bfr[4];
        #pragma unroll
        for (int rt = 0; rt < 4; ++rt)
            af[rt] = ld_frag_lds(&As[(wr * 64 + rt * 16 + ln16) * 32 + quad * 8]);
        #pragma unroll
        for (int ct = 0; ct < 4; ++ct)
            bfr[ct] = ld_frag_lds(&Bs[(wc * 64 + ct * 16 + ln16) * 32 + quad * 8]);
        #pragma unroll
        for (int rt = 0; rt < 4; ++rt)
            #pragma unroll
            for (int ct = 0; ct < 4; ++ct)
                acc[rt][ct] = MFMA16(af[rt], bfr[ct], acc[rt][ct]);
        __syncthreads();
    }
    #pragma unroll
    for (int rt = 0; rt < 4; ++rt) {
        #pragma unroll
        for (int ct = 0; ct < 4; ++ct) {
            #pragma unroll
            for (int r = 0; r < 4; ++r) {
                int row = bm + wr * 64 + rt * 16 + quad * 4 + r;
                int col = bn + wc * 64 + ct * 16 + ln16;
                Y[(size_t)row * DMODEL + col] = f2b(acc[rt][ct][r]);
            }
        }
    }
}

// =============== transpose V: v_up[b][seq][h*64+dk] -> v_t[(b*16+h)*64+dk][seq] ===============
__global__ __launch_bounds__(256) void transpose_v(const ushort_t* __restrict__ v_up,
                                                   ushort_t* __restrict__ v_t) {
    __shared__ ushort_t tile[64][68];
    const int t = threadIdx.x;
    const int s0 = blockIdx.x * 64;
    const int bh = blockIdx.y;
    const int b = bh >> 4, h = bh & 15;
    {
        const int r = t >> 2, c0 = (t & 3) * 16;
        const ushort_t* src = v_up + ((size_t)b * SEQ + s0 + r) * DMODEL + h * DK + c0;
        #pragma unroll
        for (int i = 0; i < 16; ++i) tile[r][c0 + i] = src[i];
    }
    __syncthreads();
    {
        const int c = t >> 2, r0 = (t & 3) * 16;
        ushort_t* dst = v_t + ((size_t)bh * DK + c) * SEQ + s0 + r0;
        #pragma unroll
        for (int i = 0; i < 16; ++i) dst[i] = tile[r0 + i][c];
    }
}

// =============== fused attention v5: v4 structure at the proven (512,4) occupancy ===============
// v4's __launch_bounds__(512,6) squeezed the allocator to 40 VGPR -> scratch spill (2.17 GB writes).
// (512,4) reproduces r2's 64-VGPR no-spill allocation; keep no-setprio + Pb-staged coalesced
// attn write + XCD swizzle.
#define PST 264   // P-buffer row stride in ushorts (256 + 8 pad; 528 B, 16B-aligned)
__global__ __launch_bounds__(512, 4) void attn_fused(const ushort_t* __restrict__ q_up,
                                                     const ushort_t* __restrict__ k_up,
                                                     const ushort_t* __restrict__ v_t,
                                                     const unsigned int* __restrict__ mbits,
                                                     float* __restrict__ attn,
                                                     float* __restrict__ o_ws) {
    __shared__ __align__(16) ushort_t Pb[32 * PST];   // 16,896 B
    __shared__ float psum[8][32];
    __shared__ float inv_s[32];

    const int t = threadIdx.x;
    const int w = t >> 6, lane = t & 63;
    const int ln16 = lane & 15, quad = lane >> 4;

    // XCD-aware remap: orig linear id -> (bh, q0) such that each XCD owns 4 consecutive bh.
    const int orig = blockIdx.x + gridDim.x * blockIdx.y;   // 0..2047
    const int j8 = orig >> 3;                               // 0..255
    const int bh = (orig & 7) * 4 + (j8 >> 6);              // 4 bh per XCD slot
    const int q0 = (j8 & 63) * 32;
    const int b = bh >> 4, h = bh & 15;

    // --- Q fragments (32 rows x 64 dk): A[m][k], m=ln16, k=quad*8+j
    bf16x8 aq[2][2];
    #pragma unroll
    for (int rt = 0; rt < 2; ++rt)
        #pragma unroll
        for (int ks = 0; ks < 2; ++ks)
            aq[rt][ks] = ld_frag_glb(
                &q_up[((size_t)b * SEQ + q0 + rt * 16 + ln16) * DMODEL + h * DK + ks * 32 + quad * 8]);

    const unsigned int* mrow = mbits + ((size_t)b * SEQ + q0) * (SEQ / 32);  // [row][64 words]
    const ushort_t* kbase = &k_up[(size_t)b * SEQ * DMODEL + h * DK + quad * 8];

    // --- pass 1: row sums of exp(scores)
    float rs[2][4] = {};
    for (int i = 0; i < 16; ++i) {
        const int kt = (i * 8 + w) * 16;
        bf16x8 bk0 = ld_frag_glb(kbase + (size_t)(kt + ln16) * DMODEL);
        bf16x8 bk1 = ld_frag_glb(kbase + (size_t)(kt + ln16) * DMODEL + 32);
        const int wi = kt >> 5;
        const int bsh = (kt & 16) + ln16;
        #pragma unroll
        for (int rt = 0; rt < 2; ++rt) {
            f32x4 c = {0.f, 0.f, 0.f, 0.f};
            c = MFMA16(aq[rt][0], bk0, c);
            c = MFMA16(aq[rt][1], bk1, c);
            #pragma unroll
            for (int r = 0; r < 4; ++r) {
                const int row = rt * 16 + quad * 4 + r;
                const unsigned int mw = mrow[(size_t)row * (SEQ / 32) + wi];
                const float p = ((mw >> bsh) & 1u) ? 0.f : __expf(c[r] * 0.125f);
                rs[rt][r] += p;
            }
        }
    }
    // reduce over the 16 lanes of each quad-group (cols live in ln16)
    #pragma unroll
    for (int rt = 0; rt < 2; ++rt)
        #pragma unroll
        for (int r = 0; r < 4; ++r) {
            float v = rs[rt][r];
            v += __shfl_xor(v, 1);
            v += __shfl_xor(v, 2);
            v += __shfl_xor(v, 4);
            v += __shfl_xor(v, 8);
            rs[rt][r] = v;
        }
    if (ln16 == 0) {
        #pragma unroll
        for (int rt = 0; rt < 2; ++rt)
            #pragma unroll
            for (int r = 0; r < 4; ++r)
                psum[w][rt * 16 + quad * 4 + r] = rs[rt][r];
    }
    __syncthreads();
    if (t < 32) {
        float s = 0.f;
        #pragma unroll
        for (int j = 0; j < 8; ++j) s += psum[j][t];
        inv_s[t] = 1.f / s;
    }
    __syncthreads();
    float invr[2][4];
    #pragma unroll
    for (int rt = 0; rt < 2; ++rt)
        #pragma unroll
        for (int r = 0; r < 4; ++r)
            invr[rt][r] = inv_s[rt * 16 + quad * 4 + r];

    // --- pass 2: recompute scores per 256-col block -> Pb, coalesced attn write, PV
    const int prt = w >> 2, pct = w & 3;                 // this wave's PV output tile
    f32x4 acc = {0.f, 0.f, 0.f, 0.f};
    const ushort_t* vbase = &v_t[((size_t)bh * DK + pct * 16 + ln16) * SEQ + quad * 8];
    float* abase = attn + ((size_t)bh * SEQ + q0) * SEQ;
    const ushort_t* prow = &Pb[(prt * 16 + ln16) * PST + quad * 8];
    const int arow = t >> 4;                 // attn-write row (0..31)
    const int acol0 = (t & 15) * 16;         // attn-write col base within block

    for (int kb = 0; kb < SEQ; kb += 256) {
        #pragma unroll
        for (int tl = 0; tl < 2; ++tl) {
            const int kt = kb + (w * 2 + tl) * 16;
            bf16x8 bk0 = ld_frag_glb(kbase + (size_t)(kt + ln16) * DMODEL);
            bf16x8 bk1 = ld_frag_glb(kbase + (size_t)(kt + ln16) * DMODEL + 32);
            const int wi = kt >> 5;
            const int bsh = (kt & 16) + ln16;
            #pragma unroll
            for (int rt = 0; rt < 2; ++rt) {
                f32x4 c = {0.f, 0.f, 0.f, 0.f};
                c = MFMA16(aq[rt][0], bk0, c);
                c = MFMA16(aq[rt][1], bk1, c);
                #pragma unroll
                for (int r = 0; r < 4; ++r) {
                    const int row = rt * 16 + quad * 4 + r;
                    const unsigned int mw = mrow[(size_t)row * (SEQ / 32) + wi];
                    const float p = ((mw >> bsh) & 1u) ? 0.f : __expf(c[r] * 0.125f);
                    Pb[row * PST + (kt - kb) + ln16] = f2b(p * invr[rt][r]);
                }
            }
        }
        __syncthreads();
        // coalesced attn write: each 16-lane group streams one contiguous 1 KB f32 row chunk
        {
            const ushort_t* srcp = &Pb[arow * PST + acol0];
            float* dst = abase + (size_t)arow * SEQ + kb + acol0;
            const uivec4 pa = *reinterpret_cast<const uivec4*>(srcp);
            const uivec4 pb2 = *reinterpret_cast<const uivec4*>(srcp + 8);
            __builtin_nontemporal_store(unpk2(pa[0], pa[1]), reinterpret_cast<f32x4*>(dst));
            __builtin_nontemporal_store(unpk2(pa[2], pa[3]), reinterpret_cast<f32x4*>(dst + 4));
            __builtin_nontemporal_store(unpk2(pb2[0], pb2[1]), reinterpret_cast<f32x4*>(dst + 8));
            __builtin_nontemporal_store(unpk2(pb2[2], pb2[3]), reinterpret_cast<f32x4*>(dst + 12));
        }
        // PV on the block
        #pragma unroll
        for (int k0 = 0; k0 < 256; k0 += 32) {
            bf16x8 a  = ld_frag_lds(prow + k0);
            bf16x8 vb = ld_frag_glb(vbase + kb + k0);
            acc = MFMA16(a, vb, acc);
        }
        __syncthreads();
    }
    // epilogue
    #pragma unroll
    for (int r = 0; r < 4; ++r) {
        const int row = q0 + prt * 16 + quad * 4 + r;
        const int col = h * DK + pct * 16 + ln16;
        o_ws[((size_t)b * SEQ + row) * DMODEL + col] = acc[r];
    }
}

// =============== residual + layernorm ===============
__global__ __launch_bounds__(256) void ln_kernel(const float* __restrict__ O,
                                                 const float* __restrict__ Qin,
                                                 const float* __restrict__ g,
                                                 const float* __restrict__ bt,
                                                 float* __restrict__ out) {
    __shared__ float sm[256];
    const int tid = threadIdx.x;
    const size_t base = (size_t)blockIdx.x * DMODEL;
    float v[4];
    float s = 0.f, s2 = 0.f;
    #pragma unroll
    for (int i = 0; i < 4; ++i) {
        int d = tid + i * 256;
        float x = O[base + d] + Qin[base + d];
        v[i] = x;
        s += x;
        s2 += x * x;
    }
    sm[tid] = s; __syncthreads();
    for (int st = 128; st > 0; st >>= 1) {
        if (tid < st) sm[tid] += sm[tid + st];
        __syncthreads();
    }
    s = sm[0]; __syncthreads();
    sm[tid] = s2; __syncthreads();
    for (int st = 128; st > 0; st >>= 1) {
        if (tid < st) sm[tid] += sm[tid + st];
        __syncthreads();
    }
    s2 = sm[0];
    const float mu = s * (1.0f / DMODEL);
    const float var = s2 * (1.0f / DMODEL) - mu * mu;
    const float r = rsqrtf(var + EPS);
    #pragma unroll
    for (int i = 0; i < 4; ++i) {
        int d = tid + i * 256;
        out[base + d] = (v[i] - mu) * r * g[d] + bt[d];
    }
}

extern "C" void kernel_launch(void* const* d_in, const int* in_sizes, int n_in,
                              void* d_out, int out_size, void* d_ws, size_t ws_size,
                              hipStream_t stream) {
    const float* key   = (const float*)d_in[0];
    const float* value = (const float*)d_in[1];
    const float* query = (const float*)d_in[2];
    const int*   mask  = (const int*)  d_in[3];
    const float* W_k   = (const float*)d_in[4];
    const float* W_v   = (const float*)d_in[5];
    const float* W_q   = (const float*)d_in[6];
    const float* ln_g  = (const float*)d_in[7];
    const float* ln_b  = (const float*)d_in[8];

    float* out      = (float*)d_out;                       // normed: B*L*D
    float* attn_out = out + (size_t)BATCH * SEQ * DMODEL;  // attn: B*H*L*L

    const size_t NPROJ = (size_t)BATCH * SEQ * DMODEL;     // 4,194,304
    const size_t NW    = (size_t)DMODEL * DMODEL;          // 1,048,576
    ushort_t* k_up = (ushort_t*)d_ws;
    ushort_t* v_up = k_up + NPROJ;
    ushort_t* q_up = v_up + NPROJ;
    ushort_t* v_t  = q_up + NPROJ;
    ushort_t* kb   = v_t + NPROJ;
    ushort_t* vb   = kb + NPROJ;
    ushort_t* qb   = vb + NPROJ;
    ushort_t* wtk  = qb + NPROJ;
    ushort_t* wtv  = wtk + NW;
    ushort_t* wtq  = wtv + NW;
    float*    o_ws = (float*)(wtq + NW);
    unsigned int* mbits = (unsigned int*)(o_ws + NPROJ);   // B*SEQ*64 words = 1 MiB

    const int nwords = BATCH * SEQ * (SEQ / 32);           // 262,144
    mask_to_bits<<<nwords / 256, 256, 0, stream>>>(mask, mbits);

    dim3 gcvt((unsigned)(NPROJ / (256 * 8)), 3);           // (2048, 3)
    cvt_bf16x3<<<gcvt, 256, 0, stream>>>(key, value, query, kb, vb, qb);

    dim3 gtw(DMODEL / 64, DMODEL / 64, 3);                 // (16, 16, 3)
    transpose_w3<<<gtw, 256, 0, stream>>>(W_k, W_v, W_q, wtk, wtv, wtq);

    dim3 gproj(DMODEL / 128, (BATCH * SEQ) / 128, 3);      // (8, 32, 3)
    gemm_proj3<<<gproj, 256, 0, stream>>>(kb, vb, qb, wtk, wtv, wtq, k_up, v_up, q_up);

    dim3 gtr(SEQ / 64, BATCH * NHEAD);                     // (32, 32)
    transpose_v<<<gtr, 256, 0, stream>>>(v_up, v_t);

    dim3 gat(SEQ / 32, BATCH * NHEAD);                     // (64, 32)
    attn_fused<<<gat, 512, 0, stream>>>(q_up, k_up, v_t, mbits, attn_out, o_ws);

    ln_kernel<<<BATCH * SEQ, 256, 0, stream>>>(o_ws, query, ln_g, ln_b, out);
}

// Round 9
// 915.254 us; speedup vs baseline: 1.7867x; 1.5510x over previous
//
#include <hip/hip_runtime.h>
#include <math.h>

// Problem constants
#define BATCH 2
#define SEQ   2048
#define DMODEL 1024
#define NHEAD 16
#define DK    64
#define EPS   1e-6f

typedef unsigned short ushort_t;
typedef __attribute__((ext_vector_type(8))) __bf16 bf16x8;
typedef __attribute__((ext_vector_type(4))) float f32x4;
typedef __attribute__((ext_vector_type(4))) unsigned int uivec4;
typedef __attribute__((ext_vector_type(2))) unsigned int uivec2;

union B8U { uivec4 u; bf16x8 v; };

__device__ __forceinline__ ushort_t f2b(float x) {
    union { float f; unsigned int u; } c; c.f = x;
    unsigned int r = (c.u + 0x7fffu + ((c.u >> 16) & 1u)) >> 16;
    return (ushort_t)r;
}
__device__ __forceinline__ float b2f(ushort_t b) {
    union { unsigned int u; float f; } c; c.u = ((unsigned int)b) << 16;
    return c.f;
}
__device__ __forceinline__ bf16x8 ld_frag_lds(const ushort_t* p) {
    B8U t; t.u = *reinterpret_cast<const uivec4*>(p); return t.v;
}
__device__ __forceinline__ bf16x8 ld_frag_glb(const ushort_t* p) {
    B8U t; t.u = *reinterpret_cast<const uivec4*>(p); return t.v;
}
__device__ __forceinline__ void gload_lds16(const ushort_t* g, ushort_t* l) {
    __builtin_amdgcn_global_load_lds(
        (const __attribute__((address_space(1))) unsigned int*)g,
        (__attribute__((address_space(3))) unsigned int*)l,
        16, 0, 0);
}
__device__ __forceinline__ f32x4 unpk2(unsigned int w0, unsigned int w1) {
    f32x4 o;
    o[0] = b2f((ushort_t)(w0 & 0xffffu));
    o[1] = b2f((ushort_t)(w0 >> 16));
    o[2] = b2f((ushort_t)(w1 & 0xffffu));
    o[3] = b2f((ushort_t)(w1 >> 16));
    return o;
}
#define MFMA16(a, b, c) __builtin_amdgcn_mfma_f32_16x16x32_bf16((a), (b), (c), 0, 0, 0)

// =============== mask -> bitmask: 1 bit per position, word-per-32-cols ===============
__global__ __launch_bounds__(256) void mask_to_bits(const int* __restrict__ mask,
                                                    unsigned int* __restrict__ bits) {
    const size_t widx = (size_t)blockIdx.x * 256 + threadIdx.x;
    const int4* src = reinterpret_cast<const int4*>(mask + widx * 32);
    unsigned int wv = 0;
    #pragma unroll
    for (int i = 0; i < 8; ++i) {
        int4 v = src[i];
        wv |= (v.x ? 1u : 0u) << (i * 4 + 0);
        wv |= (v.y ? 1u : 0u) << (i * 4 + 1);
        wv |= (v.z ? 1u : 0u) << (i * 4 + 2);
        wv |= (v.w ? 1u : 0u) << (i * 4 + 3);
    }
    bits[widx] = wv;
}

// =============== prep: fp32 -> bf16 for K,V,Q (elementwise, 8 elems/thread) ===============
__global__ __launch_bounds__(256) void cvt_bf16x3(const float* __restrict__ X0,
                                                  const float* __restrict__ X1,
                                                  const float* __restrict__ X2,
                                                  ushort_t* __restrict__ Y0,
                                                  ushort_t* __restrict__ Y1,
                                                  ushort_t* __restrict__ Y2) {
    const int z = blockIdx.y;
    const float* X = (z == 0) ? X0 : (z == 1) ? X1 : X2;
    ushort_t*    Y = (z == 0) ? Y0 : (z == 1) ? Y1 : Y2;
    const size_t i = ((size_t)blockIdx.x * 256 + threadIdx.x) * 8;
    float4 a = *reinterpret_cast<const float4*>(X + i);
    float4 b = *reinterpret_cast<const float4*>(X + i + 4);
    ushort_t o[8];
    o[0] = f2b(a.x); o[1] = f2b(a.y); o[2] = f2b(a.z); o[3] = f2b(a.w);
    o[4] = f2b(b.x); o[5] = f2b(b.y); o[6] = f2b(b.z); o[7] = f2b(b.w);
    *reinterpret_cast<uivec4*>(Y + i) = *reinterpret_cast<const uivec4*>(o);
}

// =============== prep: W fp32[k][n] -> Wt bf16[n][k] (64x64 LDS tiles) ===============
__global__ __launch_bounds__(256) void transpose_w3(const float* __restrict__ W0,
                                                    const float* __restrict__ W1,
                                                    const float* __restrict__ W2,
                                                    ushort_t* __restrict__ T0,
                                                    ushort_t* __restrict__ T1,
                                                    ushort_t* __restrict__ T2) {
    __shared__ ushort_t tile[64][68];
    const int z = blockIdx.z;
    const float* W = (z == 0) ? W0 : (z == 1) ? W1 : W2;
    ushort_t*    T = (z == 0) ? T0 : (z == 1) ? T1 : T2;
    const int k0 = blockIdx.x * 64;
    const int n0 = blockIdx.y * 64;
    const int t = threadIdx.x;
    {
        const int r = t >> 2, c0 = (t & 3) * 16;
        const float* src = W + (size_t)(k0 + r) * DMODEL + n0 + c0;
        #pragma unroll
        for (int i = 0; i < 16; ++i) tile[r][c0 + i] = f2b(src[i]);
    }
    __syncthreads();
    {
        const int c = t >> 2, r0 = (t & 3) * 16;
        ushort_t* dst = T + (size_t)(n0 + c) * DMODEL + k0 + r0;
        #pragma unroll
        for (int i = 0; i < 16; ++i) dst[i] = tile[r0 + i][c];
    }
}

// =============== bf16 MFMA projection GEMM (m97 structure): Y = Xb @ Wt^T ===============
__global__ __launch_bounds__(256) void gemm_proj3(const ushort_t* __restrict__ Xb0,
                                                  const ushort_t* __restrict__ Xb1,
                                                  const ushort_t* __restrict__ Xb2,
                                                  const ushort_t* __restrict__ Wt0,
                                                  const ushort_t* __restrict__ Wt1,
                                                  const ushort_t* __restrict__ Wt2,
                                                  ushort_t* __restrict__ Y0,
                                                  ushort_t* __restrict__ Y1,
                                                  ushort_t* __restrict__ Y2) {
    __shared__ __align__(16) ushort_t As[128 * 32];
    __shared__ __align__(16) ushort_t Bs[128 * 32];
    const int z = blockIdx.z;
    const ushort_t* Xb = (z == 0) ? Xb0 : (z == 1) ? Xb1 : Xb2;
    const ushort_t* Wt = (z == 0) ? Wt0 : (z == 1) ? Wt1 : Wt2;
    ushort_t*       Y  = (z == 0) ? Y0  : (z == 1) ? Y1  : Y2;

    const int t = threadIdx.x;
    const int bm = blockIdx.y * 128;
    const int bn = blockIdx.x * 128;
    const int w = t >> 6, lane = t & 63;
    const int ln16 = lane & 15, quad = lane >> 4;
    const int wr = w >> 1, wc = w & 1;

    const int srow = lane >> 2;
    const int selem = (lane & 3) * 8;

    f32x4 acc[4][4] = {};

    for (int k0 = 0; k0 < DMODEL; k0 += 32) {
        #pragma unroll
        for (int j = 0; j < 2; ++j) {
            const int g = w * 2 + j;           // 16-row group 0..7
            const int m = g * 16 + srow;
            gload_lds16(Xb + (size_t)(bm + m) * DMODEL + k0 + selem, &As[g * 512]);
            gload_lds16(Wt + (size_t)(bn + m) * DMODEL + k0 + selem, &Bs[g * 512]);
        }
        __syncthreads();
        bf16x8 af[4], bfr[4];
        #pragma unroll
        for (int rt = 0; rt < 4; ++rt)
            af[rt] = ld_frag_lds(&As[(wr * 64 + rt * 16 + ln16) * 32 + quad * 8]);
        #pragma unroll
        for (int ct = 0; ct < 4; ++ct)
            bfr[ct] = ld_frag_lds(&Bs[(wc * 64 + ct * 16 + ln16) * 32 + quad * 8]);
        #pragma unroll
        for (int rt = 0; rt < 4; ++rt)
            #pragma unroll
            for (int ct = 0; ct < 4; ++ct)
                acc[rt][ct] = MFMA16(af[rt], bfr[ct], acc[rt][ct]);
        __syncthreads();
    }
    #pragma unroll
    for (int rt = 0; rt < 4; ++rt) {
        #pragma unroll
        for (int ct = 0; ct < 4; ++ct) {
            #pragma unroll
            for (int r = 0; r < 4; ++r) {
                int row = bm + wr * 64 + rt * 16 + quad * 4 + r;
                int col = bn + wc * 64 + ct * 16 + ln16;
                Y[(size_t)row * DMODEL + col] = f2b(acc[rt][ct][r]);
            }
        }
    }
}

// =============== transpose V: v_up[b][seq][h*64+dk] -> v_t[(b*16+h)*64+dk][seq] ===============
__global__ __launch_bounds__(256) void transpose_v(const ushort_t* __restrict__ v_up,
                                                   ushort_t* __restrict__ v_t) {
    __shared__ ushort_t tile[64][68];
    const int t = threadIdx.x;
    const int s0 = blockIdx.x * 64;
    const int bh = blockIdx.y;
    const int b = bh >> 4, h = bh & 15;
    {
        const int r = t >> 2, c0 = (t & 3) * 16;
        const ushort_t* src = v_up + ((size_t)b * SEQ + s0 + r) * DMODEL + h * DK + c0;
        #pragma unroll
        for (int i = 0; i < 16; ++i) tile[r][c0 + i] = src[i];
    }
    __syncthreads();
    {
        const int c = t >> 2, r0 = (t & 3) * 16;
        ushort_t* dst = v_t + ((size_t)bh * DK + c) * SEQ + s0 + r0;
        #pragma unroll
        for (int i = 0; i < 16; ++i) dst[i] = tile[r0 + i][c];
    }
}

// =============== fused attention v6: v5 + wave-contiguous attn stores ===============
// v5's write phase had 64B-stride partial-line nt stores per instruction -> 2.7x write
// amplification (WRITE 1.45 GB) and write-bound 871 us. Fix: wave w streams rows w*4..w*4+3;
// per row, lane l reads Pb[row][l*4..l*4+3] (8B, 2-way bank = free) and nt-stores one f32x4
// at dst+l*4 -> one fully contiguous 1 KB store per instruction, all full lines.
// Keep: no setprio, XCD swizzle (FETCH 224->42 MB), __launch_bounds__(512,4) (VGPR 64, no spill).
#define PST 264   // P-buffer row stride in ushorts (256 + 8 pad; 528 B, 16B-aligned)
__global__ __launch_bounds__(512, 4) void attn_fused(const ushort_t* __restrict__ q_up,
                                                     const ushort_t* __restrict__ k_up,
                                                     const ushort_t* __restrict__ v_t,
                                                     const unsigned int* __restrict__ mbits,
                                                     float* __restrict__ attn,
                                                     float* __restrict__ o_ws) {
    __shared__ __align__(16) ushort_t Pb[32 * PST];   // 16,896 B
    __shared__ float psum[8][32];
    __shared__ float inv_s[32];

    const int t = threadIdx.x;
    const int w = t >> 6, lane = t & 63;
    const int ln16 = lane & 15, quad = lane >> 4;

    // XCD-aware remap: orig linear id -> (bh, q0) such that each XCD owns 4 consecutive bh.
    const int orig = blockIdx.x + gridDim.x * blockIdx.y;   // 0..2047
    const int j8 = orig >> 3;                               // 0..255
    const int bh = (orig & 7) * 4 + (j8 >> 6);              // 4 bh per XCD slot
    const int q0 = (j8 & 63) * 32;
    const int b = bh >> 4, h = bh & 15;

    // --- Q fragments (32 rows x 64 dk): A[m][k], m=ln16, k=quad*8+j
    bf16x8 aq[2][2];
    #pragma unroll
    for (int rt = 0; rt < 2; ++rt)
        #pragma unroll
        for (int ks = 0; ks < 2; ++ks)
            aq[rt][ks] = ld_frag_glb(
                &q_up[((size_t)b * SEQ + q0 + rt * 16 + ln16) * DMODEL + h * DK + ks * 32 + quad * 8]);

    const unsigned int* mrow = mbits + ((size_t)b * SEQ + q0) * (SEQ / 32);  // [row][64 words]
    const ushort_t* kbase = &k_up[(size_t)b * SEQ * DMODEL + h * DK + quad * 8];

    // --- pass 1: row sums of exp(scores)
    float rs[2][4] = {};
    for (int i = 0; i < 16; ++i) {
        const int kt = (i * 8 + w) * 16;
        bf16x8 bk0 = ld_frag_glb(kbase + (size_t)(kt + ln16) * DMODEL);
        bf16x8 bk1 = ld_frag_glb(kbase + (size_t)(kt + ln16) * DMODEL + 32);
        const int wi = kt >> 5;
        const int bsh = (kt & 16) + ln16;
        #pragma unroll
        for (int rt = 0; rt < 2; ++rt) {
            f32x4 c = {0.f, 0.f, 0.f, 0.f};
            c = MFMA16(aq[rt][0], bk0, c);
            c = MFMA16(aq[rt][1], bk1, c);
            #pragma unroll
            for (int r = 0; r < 4; ++r) {
                const int row = rt * 16 + quad * 4 + r;
                const unsigned int mw = mrow[(size_t)row * (SEQ / 32) + wi];
                const float p = ((mw >> bsh) & 1u) ? 0.f : __expf(c[r] * 0.125f);
                rs[rt][r] += p;
            }
        }
    }
    // reduce over the 16 lanes of each quad-group (cols live in ln16)
    #pragma unroll
    for (int rt = 0; rt < 2; ++rt)
        #pragma unroll
        for (int r = 0; r < 4; ++r) {
            float v = rs[rt][r];
            v += __shfl_xor(v, 1);
            v += __shfl_xor(v, 2);
            v += __shfl_xor(v, 4);
            v += __shfl_xor(v, 8);
            rs[rt][r] = v;
        }
    if (ln16 == 0) {
        #pragma unroll
        for (int rt = 0; rt < 2; ++rt)
            #pragma unroll
            for (int r = 0; r < 4; ++r)
                psum[w][rt * 16 + quad * 4 + r] = rs[rt][r];
    }
    __syncthreads();
    if (t < 32) {
        float s = 0.f;
        #pragma unroll
        for (int j = 0; j < 8; ++j) s += psum[j][t];
        inv_s[t] = 1.f / s;
    }
    __syncthreads();
    float invr[2][4];
    #pragma unroll
    for (int rt = 0; rt < 2; ++rt)
        #pragma unroll
        for (int r = 0; r < 4; ++r)
            invr[rt][r] = inv_s[rt * 16 + quad * 4 + r];

    // --- pass 2: recompute scores per 256-col block -> Pb, coalesced attn write, PV
    const int prt = w >> 2, pct = w & 3;                 // this wave's PV output tile
    f32x4 acc = {0.f, 0.f, 0.f, 0.f};
    const ushort_t* vbase = &v_t[((size_t)bh * DK + pct * 16 + ln16) * SEQ + quad * 8];
    float* abase = attn + ((size_t)bh * SEQ + q0) * SEQ;
    const ushort_t* prow = &Pb[(prt * 16 + ln16) * PST + quad * 8];

    for (int kb = 0; kb < SEQ; kb += 256) {
        #pragma unroll
        for (int tl = 0; tl < 2; ++tl) {
            const int kt = kb + (w * 2 + tl) * 16;
            bf16x8 bk0 = ld_frag_glb(kbase + (size_t)(kt + ln16) * DMODEL);
            bf16x8 bk1 = ld_frag_glb(kbase + (size_t)(kt + ln16) * DMODEL + 32);
            const int wi = kt >> 5;
            const int bsh = (kt & 16) + ln16;
            #pragma unroll
            for (int rt = 0; rt < 2; ++rt) {
                f32x4 c = {0.f, 0.f, 0.f, 0.f};
                c = MFMA16(aq[rt][0], bk0, c);
                c = MFMA16(aq[rt][1], bk1, c);
                #pragma unroll
                for (int r = 0; r < 4; ++r) {
                    const int row = rt * 16 + quad * 4 + r;
                    const unsigned int mw = mrow[(size_t)row * (SEQ / 32) + wi];
                    const float p = ((mw >> bsh) & 1u) ? 0.f : __expf(c[r] * 0.125f);
                    Pb[row * PST + (kt - kb) + ln16] = f2b(p * invr[rt][r]);
                }
            }
        }
        __syncthreads();
        // wave-contiguous attn write: wave w streams rows w*4..w*4+3; lane l covers cols l*4..l*4+3
        {
            #pragma unroll
            for (int rr = 0; rr < 4; ++rr) {
                const int row = w * 4 + rr;
                const uivec2 pw = *reinterpret_cast<const uivec2*>(&Pb[row * PST + lane * 4]);
                float* dst = abase + (size_t)row * SEQ + kb + lane * 4;
                __builtin_nontemporal_store(unpk2(pw[0], pw[1]), reinterpret_cast<f32x4*>(dst));
            }
        }
        // PV on the block
        #pragma unroll
        for (int k0 = 0; k0 < 256; k0 += 32) {
            bf16x8 a  = ld_frag_lds(prow + k0);
            bf16x8 vb = ld_frag_glb(vbase + kb + k0);
            acc = MFMA16(a, vb, acc);
        }
        __syncthreads();
    }
    // epilogue
    #pragma unroll
    for (int r = 0; r < 4; ++r) {
        const int row = q0 + prt * 16 + quad * 4 + r;
        const int col = h * DK + pct * 16 + ln16;
        o_ws[((size_t)b * SEQ + row) * DMODEL + col] = acc[r];
    }
}

// =============== residual + layernorm ===============
__global__ __launch_bounds__(256) void ln_kernel(const float* __restrict__ O,
                                                 const float* __restrict__ Qin,
                                                 const float* __restrict__ g,
                                                 const float* __restrict__ bt,
                                                 float* __restrict__ out) {
    __shared__ float sm[256];
    const int tid = threadIdx.x;
    const size_t base = (size_t)blockIdx.x * DMODEL;
    float v[4];
    float s = 0.f, s2 = 0.f;
    #pragma unroll
    for (int i = 0; i < 4; ++i) {
        int d = tid + i * 256;
        float x = O[base + d] + Qin[base + d];
        v[i] = x;
        s += x;
        s2 += x * x;
    }
    sm[tid] = s; __syncthreads();
    for (int st = 128; st > 0; st >>= 1) {
        if (tid < st) sm[tid] += sm[tid + st];
        __syncthreads();
    }
    s = sm[0]; __syncthreads();
    sm[tid] = s2; __syncthreads();
    for (int st = 128; st > 0; st >>= 1) {
        if (tid < st) sm[tid] += sm[tid + st];
        __syncthreads();
    }
    s2 = sm[0];
    const float mu = s * (1.0f / DMODEL);
    const float var = s2 * (1.0f / DMODEL) - mu * mu;
    const float r = rsqrtf(var + EPS);
    #pragma unroll
    for (int i = 0; i < 4; ++i) {
        int d = tid + i * 256;
        out[base + d] = (v[i] - mu) * r * g[d] + bt[d];
    }
}

extern "C" void kernel_launch(void* const* d_in, const int* in_sizes, int n_in,
                              void* d_out, int out_size, void* d_ws, size_t ws_size,
                              hipStream_t stream) {
    const float* key   = (const float*)d_in[0];
    const float* value = (const float*)d_in[1];
    const float* query = (const float*)d_in[2];
    const int*   mask  = (const int*)  d_in[3];
    const float* W_k   = (const float*)d_in[4];
    const float* W_v   = (const float*)d_in[5];
    const float* W_q   = (const float*)d_in[6];
    const float* ln_g  = (const float*)d_in[7];
    const float* ln_b  = (const float*)d_in[8];

    float* out      = (float*)d_out;                       // normed: B*L*D
    float* attn_out = out + (size_t)BATCH * SEQ * DMODEL;  // attn: B*H*L*L

    const size_t NPROJ = (size_t)BATCH * SEQ * DMODEL;     // 4,194,304
    const size_t NW    = (size_t)DMODEL * DMODEL;          // 1,048,576
    ushort_t* k_up = (ushort_t*)d_ws;
    ushort_t* v_up = k_up + NPROJ;
    ushort_t* q_up = v_up + NPROJ;
    ushort_t* v_t  = q_up + NPROJ;
    ushort_t* kb   = v_t + NPROJ;
    ushort_t* vb   = kb + NPROJ;
    ushort_t* qb   = vb + NPROJ;
    ushort_t* wtk  = qb + NPROJ;
    ushort_t* wtv  = wtk + NW;
    ushort_t* wtq  = wtv + NW;
    float*    o_ws = (float*)(wtq + NW);
    unsigned int* mbits = (unsigned int*)(o_ws + NPROJ);   // B*SEQ*64 words = 1 MiB

    const int nwords = BATCH * SEQ * (SEQ / 32);           // 262,144
    mask_to_bits<<<nwords / 256, 256, 0, stream>>>(mask, mbits);

    dim3 gcvt((unsigned)(NPROJ / (256 * 8)), 3);           // (2048, 3)
    cvt_bf16x3<<<gcvt, 256, 0, stream>>>(key, value, query, kb, vb, qb);

    dim3 gtw(DMODEL / 64, DMODEL / 64, 3);                 // (16, 16, 3)
    transpose_w3<<<gtw, 256, 0, stream>>>(W_k, W_v, W_q, wtk, wtv, wtq);

    dim3 gproj(DMODEL / 128, (BATCH * SEQ) / 128, 3);      // (8, 32, 3)
    gemm_proj3<<<gproj, 256, 0, stream>>>(kb, vb, qb, wtk, wtv, wtq, k_up, v_up, q_up);

    dim3 gtr(SEQ / 64, BATCH * NHEAD);                     // (32, 32)
    transpose_v<<<gtr, 256, 0, stream>>>(v_up, v_t);

    dim3 gat(SEQ / 32, BATCH * NHEAD);                     // (64, 32)
    attn_fused<<<gat, 512, 0, stream>>>(q_up, k_up, v_t, mbits, attn_out, o_ws);

    ln_kernel<<<BATCH * SEQ, 256, 0, stream>>>(o_ws, query, ln_g, ln_b, out);
}